// Round 1
// baseline (601.692 us; speedup 1.0000x reference)
//
#include <hip/hip_runtime.h>

typedef __bf16 bf16x8 __attribute__((ext_vector_type(8)));
typedef float  f32x4  __attribute__((ext_vector_type(4)));

#define NROWS 8192
#define DK    4096
#define MCOLS 4096
#define BM 128
#define BN 128
#define BK 32
#define KT (DK / BK)   // 128 k-tiles

struct Stage {
  float4 x0a, x0b, x1a, x1b;   // X tile: row srow (8 floats), row srow+64
  float4 a0a, a0b, a1a, a1b;   // A tile: same pattern
};

__device__ __forceinline__ bf16x8 pack8(const float4& a, const float4& b) {
  bf16x8 r;
  r[0] = (__bf16)a.x; r[1] = (__bf16)a.y; r[2] = (__bf16)a.z; r[3] = (__bf16)a.w;
  r[4] = (__bf16)b.x; r[5] = (__bf16)b.y; r[6] = (__bf16)b.z; r[7] = (__bf16)b.w;
  return r;
}

__global__ __launch_bounds__(256) void gemm_rowsq(const float* __restrict__ X,
                                                  const float* __restrict__ A,
                                                  float* __restrict__ out) {
  __shared__ __align__(16) __bf16 Xs[BM * BK];
  __shared__ __align__(16) __bf16 As[BN * BK];
  __shared__ float rowsum[2][BM];

  const int t    = threadIdx.x;
  const int lane = t & 63;
  const int wid  = t >> 6;
  const int wr   = wid >> 1;    // wave row (0..1): rows wr*64..+63
  const int wc   = wid & 1;     // wave col (0..1): cols wc*64..+63
  const int l15  = lane & 15;
  const int lg   = lane >> 4;   // 0..3

  // XCD-aware bijective swizzle: 2048 blocks, 8 XCDs, 256 per XCD
  unsigned bid = blockIdx.x;
  unsigned swz = (bid & 7) * 256u + (bid >> 3);
  const int tile_m = swz >> 5;   // 0..63  (x row tile)
  const int tile_n = swz & 31;   // 0..31  (A row tile = output col tile)

  // staging geometry: thread t stages rows {t>>2, t>>2+64}, k-chunk (t&3)*8
  const int srow = t >> 2;
  const int sc   = t & 3;
  const int cw   = sc ^ ((t >> 3) & 3);        // XOR chunk swizzle (2-way free)
  const int woff = srow * BK + cw * 8;

  const float* gx = X + (size_t)(tile_m * BM + srow) * DK + sc * 8;
  const float* ga = A + (size_t)(tile_n * BN + srow) * DK + sc * 8;

  // fragment-read geometry (swizzle reduces to lane-constant: lg ^ ((l15>>1)&3))
  const int chA  = lg ^ ((l15 >> 1) & 3);
  const int aoff = (wr * 64 + l15) * BK + chA * 8;
  const int boff = (wc * 64 + l15) * BK + chA * 8;

  f32x4 acc[4][4] = {};

  auto load_tile = [&](int kt) {
    Stage s;
    const float* px = gx + kt * BK;
    const float* pa = ga + kt * BK;
    s.x0a = *(const float4*)(px);
    s.x0b = *(const float4*)(px + 4);
    s.x1a = *(const float4*)(px + (size_t)64 * DK);
    s.x1b = *(const float4*)(px + (size_t)64 * DK + 4);
    s.a0a = *(const float4*)(pa);
    s.a0b = *(const float4*)(pa + 4);
    s.a1a = *(const float4*)(pa + (size_t)64 * DK);
    s.a1b = *(const float4*)(pa + (size_t)64 * DK + 4);
    return s;
  };

  auto store_stage = [&](const Stage& s) {
    *(bf16x8*)(Xs + woff)           = pack8(s.x0a, s.x0b);
    *(bf16x8*)(Xs + woff + 64 * BK) = pack8(s.x1a, s.x1b);
    *(bf16x8*)(As + woff)           = pack8(s.a0a, s.a0b);
    *(bf16x8*)(As + woff + 64 * BK) = pack8(s.a1a, s.a1b);
  };

  auto compute = [&]() {
    bf16x8 af[4], bfr[4];
#pragma unroll
    for (int m = 0; m < 4; ++m)
      af[m] = *(const bf16x8*)(Xs + aoff + m * 16 * BK);
#pragma unroll
    for (int n = 0; n < 4; ++n)
      bfr[n] = *(const bf16x8*)(As + boff + n * 16 * BK);
#pragma unroll
    for (int m = 0; m < 4; ++m)
#pragma unroll
      for (int n = 0; n < 4; ++n)
        acc[m][n] = __builtin_amdgcn_mfma_f32_16x16x32_bf16(af[m], bfr[n],
                                                            acc[m][n], 0, 0, 0);
  };

  Stage sa = load_tile(0), sb;

  for (int kt = 0; kt < KT; kt += 2) {
    // even half: compute tile kt, prefetch kt+1
    __syncthreads();                 // prev reads done; LDS reusable
    store_stage(sa);
    sb = load_tile(kt + 1);          // HBM latency hides under MFMA below
    __syncthreads();                 // staged tile visible
    compute();
    // odd half: compute tile kt+1, prefetch kt+2
    __syncthreads();
    store_stage(sb);
    if (kt + 2 < KT) sa = load_tile(kt + 2);
    __syncthreads();
    compute();
  }

  // ---- epilogue: row sums of squares ----
  // acc[m][n][j]: row = wr*64 + m*16 + lg*4 + j, col = wc*64 + n*16 + l15
  float v[4][4];
#pragma unroll
  for (int m = 0; m < 4; ++m)
#pragma unroll
    for (int j = 0; j < 4; ++j) {
      float s = 0.f;
#pragma unroll
      for (int n = 0; n < 4; ++n) {
        float c = acc[m][n][j];
        s += c * c;
      }
      s += __shfl_xor(s, 1, 64);
      s += __shfl_xor(s, 2, 64);
      s += __shfl_xor(s, 4, 64);
      s += __shfl_xor(s, 8, 64);
      v[m][j] = s;
    }

  if (l15 == 0) {
#pragma unroll
    for (int m = 0; m < 4; ++m)
#pragma unroll
      for (int j = 0; j < 4; ++j)
        rowsum[wc][wr * 64 + m * 16 + lg * 4 + j] = v[m][j];
  }
  __syncthreads();

  if (t < BM) {
    float p = rowsum[0][t] + rowsum[1][t];
    atomicAdd(&out[tile_m * BM + t], p);
  }
}

extern "C" void kernel_launch(void* const* d_in, const int* in_sizes, int n_in,
                              void* d_out, int out_size, void* d_ws, size_t ws_size,
                              hipStream_t stream) {
  const float* x = (const float*)d_in[0];
  const float* A = (const float*)d_in[1];
  float* out = (float*)d_out;

  hipMemsetAsync(out, 0, (size_t)out_size * sizeof(float), stream);

  dim3 grid((NROWS / BM) * (MCOLS / BN));  // 64 * 32 = 2048 blocks
  dim3 block(256);
  hipLaunchKernelGGL(gemm_rowsq, grid, block, 0, stream, x, A, out);
}

// Round 2
// 309.753 us; speedup vs baseline: 1.9425x; 1.9425x over previous
//
#include <hip/hip_runtime.h>

typedef __bf16 bf16x8 __attribute__((ext_vector_type(8)));
typedef float  f32x4  __attribute__((ext_vector_type(4)));

#define NROWS 8192
#define DK    4096
#define MCOLS 4096
#define BM 128
#define BN 128
#define BK 32
#define KT (DK / BK)   // 128 k-tiles

#define X_ELEMS ((size_t)NROWS * DK)
#define A_ELEMS ((size_t)MCOLS * DK)
#define WS_NEED ((X_ELEMS + A_ELEMS) * 2)   // bytes of bf16 ws

__device__ __forceinline__ bf16x8 pack8(const float4& a, const float4& b) {
  bf16x8 r;
  r[0] = (__bf16)a.x; r[1] = (__bf16)a.y; r[2] = (__bf16)a.z; r[3] = (__bf16)a.w;
  r[4] = (__bf16)b.x; r[5] = (__bf16)b.y; r[6] = (__bf16)b.z; r[7] = (__bf16)b.w;
  return r;
}

__device__ __forceinline__ void gload_lds16(const __bf16* g, __bf16* l) {
  __builtin_amdgcn_global_load_lds(
      (const __attribute__((address_space(1))) void*)g,
      (__attribute__((address_space(3))) void*)l, 16, 0, 0);
}

// fp32 [rows][4096] -> bf16 tile-major [rows/128][KT][128][32], chunk-swizzled
// (element (rloc, c*8+j) stored at chunk c ^ ((rloc>>1)&3)).
__global__ __launch_bounds__(256) void convert_swz(const float* __restrict__ src,
                                                   __bf16* __restrict__ dst,
                                                   int rows) {
  int total = rows * 512;                  // 8-elem chunks
  for (int i = blockIdx.x * blockDim.x + threadIdx.x; i < total;
       i += gridDim.x * blockDim.x) {
    int r = i >> 9, g = i & 511;
    int kt = g >> 2, c = g & 3;
    const float4* p = (const float4*)(src + (size_t)r * DK + (size_t)g * 8);
    float4 a = p[0], b = p[1];
    int rloc = r & 127, tm = r >> 7;
    int cw = c ^ ((rloc >> 1) & 3);
    __bf16* q = dst + (((size_t)tm * KT + kt) * 128 + rloc) * 32 + cw * 8;
    *(bf16x8*)q = pack8(a, b);
  }
}

// m97-structure GEMM from pre-swizzled bf16 ws, fused row-sum-of-squares.
__global__ __launch_bounds__(256) void gemm_ws(const __bf16* __restrict__ wsX,
                                               const __bf16* __restrict__ wsA,
                                               float* __restrict__ out) {
  __shared__ __align__(16) __bf16 Xs[BM * BK];   // 8 KB
  __shared__ __align__(16) __bf16 As[BN * BK];   // 8 KB
  __shared__ float rowsum[2][BM];

  const int t    = threadIdx.x;
  const int lane = t & 63;
  const int w    = t >> 6;
  const int wr   = w >> 1;
  const int wc   = w & 1;
  const int l15  = lane & 15;
  const int lg   = lane >> 4;

  // XCD-aware order; within XCD: n-pairs inner so 2MB A-group + 1MB X-panel fit L2
  unsigned bid = blockIdx.x;            // 2048 blocks
  unsigned xcd = bid & 7, seq = bid >> 3;
  int ni = seq & 1;
  int mm = (seq >> 1) & 7;
  int no = seq >> 4;                    // 0..15
  const int tile_m = xcd * 8 + mm;      // 0..63
  const int tile_n = no * 2 + ni;       // 0..31

  const __bf16* gx = wsX + (size_t)tile_m * ((size_t)KT * BM * BK);
  const __bf16* ga = wsA + (size_t)tile_n * ((size_t)KT * BN * BK);

  // fragment-read geometry (chunk swizzle reduces to lane-constant)
  const int chA   = lg ^ ((l15 >> 1) & 3);
  const int xbase = (wr * 64 + l15) * BK + chA * 8;
  const int abase = (wc * 64 + l15) * BK + chA * 8;

  f32x4 acc[4][4] = {};

  const int soff = t * 8;        // element offset for this thread's 16B stage
  __bf16* xdst = Xs + w * 512;   // wave-uniform LDS bases
  __bf16* adst = As + w * 512;

  for (int kt = 0; kt < KT; ++kt) {
    const __bf16* px = gx + (size_t)kt * (BM * BK);
    const __bf16* pa = ga + (size_t)kt * (BN * BK);
    __syncthreads();                         // prior reads done; LDS reusable
    gload_lds16(px + soff,        xdst);
    gload_lds16(px + soff + 2048, xdst + 2048);
    gload_lds16(pa + soff,        adst);
    gload_lds16(pa + soff + 2048, adst + 2048);
    __syncthreads();                         // vmcnt(0) drained before barrier

    bf16x8 af[4], bfr[4];
#pragma unroll
    for (int m = 0; m < 4; ++m)
      af[m] = *(const bf16x8*)(Xs + xbase + m * 16 * BK);
#pragma unroll
    for (int n = 0; n < 4; ++n)
      bfr[n] = *(const bf16x8*)(As + abase + n * 16 * BK);
#pragma unroll
    for (int m = 0; m < 4; ++m)
#pragma unroll
      for (int n = 0; n < 4; ++n)
        acc[m][n] = __builtin_amdgcn_mfma_f32_16x16x32_bf16(af[m], bfr[n],
                                                            acc[m][n], 0, 0, 0);
  }

  // epilogue: row sums of squares
  float v[4][4];
#pragma unroll
  for (int m = 0; m < 4; ++m)
#pragma unroll
    for (int j = 0; j < 4; ++j) {
      float s = 0.f;
#pragma unroll
      for (int n = 0; n < 4; ++n) {
        float c = acc[m][n][j];
        s += c * c;
      }
      s += __shfl_xor(s, 1, 64);
      s += __shfl_xor(s, 2, 64);
      s += __shfl_xor(s, 4, 64);
      s += __shfl_xor(s, 8, 64);
      v[m][j] = s;
    }

  if (l15 == 0) {
#pragma unroll
    for (int m = 0; m < 4; ++m)
#pragma unroll
      for (int j = 0; j < 4; ++j)
        rowsum[wc][wr * 64 + m * 16 + lg * 4 + j] = v[m][j];
  }
  __syncthreads();

  if (t < BM) {
    float p = rowsum[0][t] + rowsum[1][t];
    atomicAdd(&out[tile_m * BM + t], p);
  }
}

// ---------------- fallback (R1 kernel, used only if ws too small) -----------
struct Stage {
  float4 x0a, x0b, x1a, x1b;
  float4 a0a, a0b, a1a, a1b;
};

__global__ __launch_bounds__(256) void gemm_rowsq(const float* __restrict__ X,
                                                  const float* __restrict__ A,
                                                  float* __restrict__ out) {
  __shared__ __align__(16) __bf16 Xs[BM * BK];
  __shared__ __align__(16) __bf16 As[BN * BK];
  __shared__ float rowsum[2][BM];

  const int t    = threadIdx.x;
  const int lane = t & 63;
  const int wid  = t >> 6;
  const int wr   = wid >> 1;
  const int wc   = wid & 1;
  const int l15  = lane & 15;
  const int lg   = lane >> 4;

  unsigned bid = blockIdx.x;
  unsigned swz = (bid & 7) * 256u + (bid >> 3);
  const int tile_m = swz >> 5;
  const int tile_n = swz & 31;

  const int srow = t >> 2;
  const int sc   = t & 3;
  const int cw   = sc ^ ((t >> 3) & 3);
  const int woff = srow * BK + cw * 8;

  const float* gx = X + (size_t)(tile_m * BM + srow) * DK + sc * 8;
  const float* ga = A + (size_t)(tile_n * BN + srow) * DK + sc * 8;

  const int chA  = lg ^ ((l15 >> 1) & 3);
  const int aoff = (wr * 64 + l15) * BK + chA * 8;
  const int boff = (wc * 64 + l15) * BK + chA * 8;

  f32x4 acc[4][4] = {};

  auto load_tile = [&](int kt) {
    Stage s;
    const float* px = gx + kt * BK;
    const float* pa = ga + kt * BK;
    s.x0a = *(const float4*)(px);
    s.x0b = *(const float4*)(px + 4);
    s.x1a = *(const float4*)(px + (size_t)64 * DK);
    s.x1b = *(const float4*)(px + (size_t)64 * DK + 4);
    s.a0a = *(const float4*)(pa);
    s.a0b = *(const float4*)(pa + 4);
    s.a1a = *(const float4*)(pa + (size_t)64 * DK);
    s.a1b = *(const float4*)(pa + (size_t)64 * DK + 4);
    return s;
  };

  auto store_stage = [&](const Stage& s) {
    *(bf16x8*)(Xs + woff)           = pack8(s.x0a, s.x0b);
    *(bf16x8*)(Xs + woff + 64 * BK) = pack8(s.x1a, s.x1b);
    *(bf16x8*)(As + woff)           = pack8(s.a0a, s.a0b);
    *(bf16x8*)(As + woff + 64 * BK) = pack8(s.a1a, s.a1b);
  };

  auto compute = [&]() {
    bf16x8 af[4], bfr[4];
#pragma unroll
    for (int m = 0; m < 4; ++m)
      af[m] = *(const bf16x8*)(Xs + aoff + m * 16 * BK);
#pragma unroll
    for (int n = 0; n < 4; ++n)
      bfr[n] = *(const bf16x8*)(As + boff + n * 16 * BK);
#pragma unroll
    for (int m = 0; m < 4; ++m)
#pragma unroll
      for (int n = 0; n < 4; ++n)
        acc[m][n] = __builtin_amdgcn_mfma_f32_16x16x32_bf16(af[m], bfr[n],
                                                            acc[m][n], 0, 0, 0);
  };

  Stage sa = load_tile(0), sb;

  for (int kt = 0; kt < KT; kt += 2) {
    __syncthreads();
    store_stage(sa);
    sb = load_tile(kt + 1);
    __syncthreads();
    compute();
    __syncthreads();
    store_stage(sb);
    if (kt + 2 < KT) sa = load_tile(kt + 2);
    __syncthreads();
    compute();
  }

  float v[4][4];
#pragma unroll
  for (int m = 0; m < 4; ++m)
#pragma unroll
    for (int j = 0; j < 4; ++j) {
      float s = 0.f;
#pragma unroll
      for (int n = 0; n < 4; ++n) {
        float c = acc[m][n][j];
        s += c * c;
      }
      s += __shfl_xor(s, 1, 64);
      s += __shfl_xor(s, 2, 64);
      s += __shfl_xor(s, 4, 64);
      s += __shfl_xor(s, 8, 64);
      v[m][j] = s;
    }

  if (l15 == 0) {
#pragma unroll
    for (int m = 0; m < 4; ++m)
#pragma unroll
      for (int j = 0; j < 4; ++j)
        rowsum[wc][wr * 64 + m * 16 + lg * 4 + j] = v[m][j];
  }
  __syncthreads();

  if (t < BM) {
    float p = rowsum[0][t] + rowsum[1][t];
    atomicAdd(&out[tile_m * BM + t], p);
  }
}

extern "C" void kernel_launch(void* const* d_in, const int* in_sizes, int n_in,
                              void* d_out, int out_size, void* d_ws, size_t ws_size,
                              hipStream_t stream) {
  const float* x = (const float*)d_in[0];
  const float* A = (const float*)d_in[1];
  float* out = (float*)d_out;

  hipMemsetAsync(out, 0, (size_t)out_size * sizeof(float), stream);

  if (ws_size >= WS_NEED) {
    __bf16* wsX = (__bf16*)d_ws;
    __bf16* wsA = wsX + X_ELEMS;
    hipLaunchKernelGGL(convert_swz, dim3(2048), dim3(256), 0, stream, x, wsX, NROWS);
    hipLaunchKernelGGL(convert_swz, dim3(2048), dim3(256), 0, stream, A, wsA, MCOLS);
    hipLaunchKernelGGL(gemm_ws, dim3((NROWS / BM) * (MCOLS / BN)), dim3(256), 0,
                       stream, wsX, wsA, out);
  } else {
    hipLaunchKernelGGL(gemm_rowsq, dim3((NROWS / BM) * (MCOLS / BN)), dim3(256), 0,
                       stream, x, A, out);
  }
}

// Round 4
// 271.495 us; speedup vs baseline: 2.2162x; 1.1409x over previous
//
#include <hip/hip_runtime.h>

typedef __bf16 bf16x8 __attribute__((ext_vector_type(8)));
typedef float  f32x4  __attribute__((ext_vector_type(4)));

#define NROWS 8192
#define DK    4096
#define MCOLS 4096
#define NKT   64            // K-tiles of BK=64
#define IMG   16384         // bf16 elems per 256x64 tile image (32 KB)
#define X_TILES 32
#define W_TILES 16

#define X_ELEMS ((size_t)NROWS * DK)
#define A_ELEMS ((size_t)MCOLS * DK)
#define WS_NEED ((X_ELEMS + A_ELEMS) * 2)

#define BAR()  do { __builtin_amdgcn_s_barrier(); asm volatile("" ::: "memory"); } while (0)
#define LGKM0  asm volatile("s_waitcnt lgkmcnt(0)" ::: "memory")
#define VM(n)  asm volatile("s_waitcnt vmcnt(" #n ")" ::: "memory")

__device__ __forceinline__ bf16x8 pack8(const float4& a, const float4& b) {
  bf16x8 r;
  r[0] = (__bf16)a.x; r[1] = (__bf16)a.y; r[2] = (__bf16)a.z; r[3] = (__bf16)a.w;
  r[4] = (__bf16)b.x; r[5] = (__bf16)b.y; r[6] = (__bf16)b.z; r[7] = (__bf16)b.w;
  return r;
}

__device__ __forceinline__ void gload16(const __bf16* g, __bf16* l) {
  __builtin_amdgcn_global_load_lds(
      (const __attribute__((address_space(1))) void*)g,
      (__attribute__((address_space(3))) void*)l, 16, 0, 0);
}

// ---- converts: fp32 row-major -> bf16 fragment-major tile images -----------
// X image slot = mh*8 + wr4*2 + m2  (m_frag = wr4*4 + mh*2 + m2)
__global__ __launch_bounds__(256) void convX(const float* __restrict__ src,
                                             __bf16* __restrict__ dst) {
  const int total = X_TILES * NKT * 2048;
  for (int i = blockIdx.x * blockDim.x + threadIdx.x; i < total;
       i += gridDim.x * blockDim.x) {
    int lane = i & 63;
    int kc   = (i >> 6) & 1;
    int slot = (i >> 7) & 15;
    int kt   = (i >> 11) & 63;
    int tm   = i >> 17;
    int mh = slot >> 3, wr4 = (slot >> 1) & 3, m2 = slot & 1;
    int mfrag = wr4 * 4 + mh * 2 + m2;
    int row = tm * 256 + mfrag * 16 + (lane & 15);
    int k   = kt * 64 + kc * 32 + (lane >> 4) * 8;
    const float4* p = (const float4*)(src + (size_t)row * DK + k);
    float4 a = p[0], b = p[1];
    *(bf16x8*)(dst + (size_t)i * 8) = pack8(a, b);
  }
}

// W image slot = nh*8 + wc2*4 + n4  (n_frag = wc2*8 + nh*4 + n4)
__global__ __launch_bounds__(256) void convW(const float* __restrict__ src,
                                             __bf16* __restrict__ dst) {
  const int total = W_TILES * NKT * 2048;
  for (int i = blockIdx.x * blockDim.x + threadIdx.x; i < total;
       i += gridDim.x * blockDim.x) {
    int lane = i & 63;
    int kc   = (i >> 6) & 1;
    int slot = (i >> 7) & 15;
    int kt   = (i >> 11) & 63;
    int tn   = i >> 17;
    int nh = slot >> 3, wc2 = (slot >> 2) & 1, n4 = slot & 3;
    int nfrag = wc2 * 8 + nh * 4 + n4;
    int row = tn * 256 + nfrag * 16 + (lane & 15);
    int k   = kt * 64 + kc * 32 + (lane >> 4) * 8;
    const float4* p = (const float4*)(src + (size_t)row * DK + k);
    float4 a = p[0], b = p[1];
    *(bf16x8*)(dst + (size_t)i * 8) = pack8(a, b);
  }
}

// ---- 8-phase 256^2 GEMM + fused row-sum-of-squares -------------------------
__device__ __forceinline__ void readA(bf16x8 (&a)[2][2], const __bf16* p, int MH) {
#pragma unroll
  for (int m2 = 0; m2 < 2; ++m2)
#pragma unroll
    for (int kc = 0; kc < 2; ++kc)
      a[m2][kc] = *(const bf16x8*)(p + MH * 8192 + m2 * 1024 + kc * 512);
}

__device__ __forceinline__ void readB(bf16x8 (&b)[4][2], const __bf16* p, int NH) {
#pragma unroll
  for (int n4 = 0; n4 < 4; ++n4)
#pragma unroll
    for (int kc = 0; kc < 2; ++kc)
      b[n4][kc] = *(const bf16x8*)(p + NH * 8192 + n4 * 1024 + kc * 512);
}

__device__ __forceinline__ void quad(f32x4 (&acc)[4][8], const bf16x8 (&a)[2][2],
                                     const bf16x8 (&b)[4][2], int MH, int NH) {
  __builtin_amdgcn_s_setprio(1);
#pragma unroll
  for (int m2 = 0; m2 < 2; ++m2)
#pragma unroll
    for (int n4 = 0; n4 < 4; ++n4)
#pragma unroll
      for (int kc = 0; kc < 2; ++kc)
        acc[MH * 2 + m2][NH * 4 + n4] = __builtin_amdgcn_mfma_f32_16x16x32_bf16(
            a[m2][kc], b[n4][kc], acc[MH * 2 + m2][NH * 4 + n4], 0, 0, 0);
  __builtin_amdgcn_s_setprio(0);
}

__global__ __launch_bounds__(512, 2) void gemm8(const __bf16* __restrict__ wsX,
                                                const __bf16* __restrict__ wsW,
                                                float* __restrict__ out) {
  __shared__ __align__(16) __bf16 Xls[2][IMG];   // 64 KB
  __shared__ __align__(16) __bf16 Wls[2][IMG];   // 64 KB
  __shared__ float rowsum[2][256];

  const int t    = threadIdx.x;
  const int lane = t & 63;
  const int w    = t >> 6;           // 0..7
  const int wr4  = w >> 1;           // 0..3 : rows wr4*64..+63
  const int wc2  = w & 1;            // 0..1 : cols wc2*128..+127
  const int l15  = lane & 15;
  const int lg   = lane >> 4;

  // 512 blocks -> 8 XCDs x 64 (bijective; 512 % 8 == 0)
  unsigned bid = blockIdx.x;
  unsigned swz = (bid & 7) * 64u + (bid >> 3);
  const int tile_m = swz >> 4;       // 0..31
  const int tile_n = swz & 15;       // 0..15

  const __bf16* xbase = wsX + (size_t)tile_m * ((size_t)NKT * IMG);
  const __bf16* wbase = wsW + (size_t)tile_n * ((size_t)NKT * IMG);

  const __bf16* pX0 = &Xls[0][0] + wr4 * 2048 + lane * 8;
  const __bf16* pX1 = &Xls[1][0] + wr4 * 2048 + lane * 8;
  const __bf16* pW0 = &Wls[0][0] + wc2 * 4096 + lane * 8;
  const __bf16* pW1 = &Wls[1][0] + wc2 * 4096 + lane * 8;

  f32x4 acc[4][8] = {};
  bf16x8 a[2][2], b0[4][2], b1[4][2];

  auto stage = [&](const __bf16* srcImg, int regionOff, __bf16* ldsImg) {
    const __bf16* s0 = srcImg + regionOff + t * 8;
    __bf16* d0 = ldsImg + regionOff + w * 512;   // wave-uniform dst
    gload16(s0, d0);
    gload16(s0 + 4096, d0 + 4096);
  };

  // prologue: prime 6 region-stages in steady-state FIFO order
  stage(xbase,          0, &Xls[0][0]);   // X0(0)   s1
  stage(wbase,          0, &Wls[0][0]);   // W0(0)   s2
  stage(xbase,       8192, &Xls[0][0]);   // X1(0)   s3
  stage(wbase,       8192, &Wls[0][0]);   // W1(0)   s4
  stage(xbase + IMG,    0, &Xls[1][0]);   // X0(1)   s5
  stage(wbase + IMG,    0, &Wls[1][0]);   // W0(1)   s6
  VM(8);                                  // own X0(0),W0(0) landed
  BAR();                                  // ALL waves' X0(0),W0(0) landed

  for (int it = 0; it < 31; ++it) {
    const int h0 = 2 * it;
    const __bf16* xi1 = xbase + (size_t)(h0 + 1) * IMG;
    const __bf16* wi1 = wbase + (size_t)(h0 + 1) * IMG;
    const __bf16* xi2 = xbase + (size_t)(h0 + 2) * IMG;
    const __bf16* wi2 = wbase + (size_t)(h0 + 2) * IMG;
    const __bf16* xi3 = xbase + (size_t)(h0 + 3) * IMG;
    const __bf16* wi3 = wbase + (size_t)(h0 + 3) * IMG;

    // ---- half-iter A: tile h0 in buf0 ----
    // ph1 (X0,W0 of h0 guaranteed by previous VM(8)+BAR)
    readA(a, pX0, 0); readB(b0, pW0, 0);
    stage(xi1, 8192, &Xls[1][0]);                 // X1(h0+1) -> buf1
    BAR(); LGKM0; quad(acc, a, b0, 0, 0); VM(6); BAR();   // forces X1,W1(h0)
    // ph2
    readB(b1, pW0, 1);
    stage(wi1, 8192, &Wls[1][0]);                 // W1(h0+1) -> buf1
    BAR(); LGKM0; quad(acc, a, b1, 0, 1); BAR();
    // ph3
    readA(a, pX0, 1);
    stage(xi2, 0, &Xls[0][0]);                    // X0(h0+2) -> buf0
    BAR(); LGKM0; quad(acc, a, b0, 1, 0); BAR();
    // ph4
    stage(wi2, 0, &Wls[0][0]);                    // W0(h0+2) -> buf0
    BAR(); quad(acc, a, b1, 1, 1); VM(8); BAR();  // forces X0,W0(h0+1)

    // ---- half-iter B: tile h0+1 in buf1 ----
    // ph5
    readA(a, pX1, 0); readB(b0, pW1, 0);
    stage(xi2, 8192, &Xls[0][0]);                 // X1(h0+2) -> buf0
    BAR(); LGKM0; quad(acc, a, b0, 0, 0); VM(6); BAR();   // forces X1,W1(h0+1)
    // ph6
    readB(b1, pW1, 1);
    stage(wi2, 8192, &Wls[0][0]);                 // W1(h0+2) -> buf0
    BAR(); LGKM0; quad(acc, a, b1, 0, 1); BAR();
    // ph7
    readA(a, pX1, 1);
    stage(xi3, 0, &Xls[1][0]);                    // X0(h0+3) -> buf1
    BAR(); LGKM0; quad(acc, a, b0, 1, 0); BAR();
    // ph8
    stage(wi3, 0, &Wls[1][0]);                    // W0(h0+3) -> buf1
    BAR(); quad(acc, a, b1, 1, 1); VM(8); BAR();  // forces X0,W0(h0+2)
  }

  // ---- peeled tail: it = 31 (tiles 62 in buf0, 63 in buf1) ----
  {
    const __bf16* xi1 = xbase + (size_t)63 * IMG;
    const __bf16* wi1 = wbase + (size_t)63 * IMG;

    // ph1 (X0,W0(62) ready)
    readA(a, pX0, 0); readB(b0, pW0, 0);
    stage(xi1, 8192, &Xls[1][0]);                 // X1(63) -> buf1
    BAR(); LGKM0; quad(acc, a, b0, 0, 0); VM(6); BAR();   // forces X1,W1(62)
    // ph2
    readB(b1, pW0, 1);
    stage(wi1, 8192, &Wls[1][0]);                 // W1(63) -> buf1
    BAR(); LGKM0; quad(acc, a, b1, 0, 1); BAR();
    // ph3
    readA(a, pX0, 1);
    BAR(); LGKM0; quad(acc, a, b0, 1, 0); BAR();
    // ph4
    BAR(); quad(acc, a, b1, 1, 1); VM(4); BAR();  // forces X0,W0(63)
    // ph5
    readA(a, pX1, 0); readB(b0, pW1, 0);
    BAR(); LGKM0; quad(acc, a, b0, 0, 0); VM(0); BAR();   // forces X1,W1(63)
    // ph6
    readB(b1, pW1, 1);
    BAR(); LGKM0; quad(acc, a, b1, 0, 1); BAR();
    // ph7
    readA(a, pX1, 1);
    BAR(); LGKM0; quad(acc, a, b0, 1, 0); BAR();
    // ph8
    quad(acc, a, b1, 1, 1);
  }

  // ---- epilogue: row sums of squares ----
  // acc[mr][nc][j]: row = tile_m*256 + (wr4*4+mr)*16 + lg*4 + j
  float v[4][4];
#pragma unroll
  for (int mr = 0; mr < 4; ++mr)
#pragma unroll
    for (int j = 0; j < 4; ++j) {
      float s = 0.f;
#pragma unroll
      for (int nc = 0; nc < 8; ++nc) {
        float c = acc[mr][nc][j];
        s += c * c;
      }
      s += __shfl_xor(s, 1, 64);
      s += __shfl_xor(s, 2, 64);
      s += __shfl_xor(s, 4, 64);
      s += __shfl_xor(s, 8, 64);
      v[mr][j] = s;
    }

  if (l15 == 0) {
#pragma unroll
    for (int mr = 0; mr < 4; ++mr)
#pragma unroll
      for (int j = 0; j < 4; ++j)
        rowsum[wc2][(wr4 * 4 + mr) * 16 + lg * 4 + j] = v[mr][j];
  }
  __syncthreads();

  if (t < 256) {
    float p = rowsum[0][t] + rowsum[1][t];
    atomicAdd(&out[tile_m * 256 + t], p);
  }
}

// ---------------- fallback (direct fp32 path, used only if ws too small) ----
struct Stage {
  float4 x0a, x0b, x1a, x1b;
  float4 a0a, a0b, a1a, a1b;
};

__global__ __launch_bounds__(256) void gemm_rowsq(const float* __restrict__ X,
                                                  const float* __restrict__ A,
                                                  float* __restrict__ out) {
  __shared__ __align__(16) __bf16 Xs[128 * 32];
  __shared__ __align__(16) __bf16 As[128 * 32];
  __shared__ float rowsum[2][128];

  const int t    = threadIdx.x;
  const int lane = t & 63;
  const int wid  = t >> 6;
  const int wr   = wid >> 1;
  const int wc   = wid & 1;
  const int l15  = lane & 15;
  const int lg   = lane >> 4;

  unsigned bid = blockIdx.x;
  unsigned swz = (bid & 7) * 256u + (bid >> 3);
  const int tile_m = swz >> 5;
  const int tile_n = swz & 31;

  const int srow = t >> 2;
  const int sc   = t & 3;
  const int cw   = sc ^ ((t >> 3) & 3);
  const int woff = srow * 32 + cw * 8;

  const float* gx = X + (size_t)(tile_m * 128 + srow) * DK + sc * 8;
  const float* ga = A + (size_t)(tile_n * 128 + srow) * DK + sc * 8;

  const int chA  = lg ^ ((l15 >> 1) & 3);
  const int aoff = (wr * 64 + l15) * 32 + chA * 8;
  const int boff = (wc * 64 + l15) * 32 + chA * 8;

  f32x4 acc[4][4] = {};

  auto load_tile = [&](int kt) {
    Stage s;
    const float* px = gx + kt * 32;
    const float* pa = ga + kt * 32;
    s.x0a = *(const float4*)(px);
    s.x0b = *(const float4*)(px + 4);
    s.x1a = *(const float4*)(px + (size_t)64 * DK);
    s.x1b = *(const float4*)(px + (size_t)64 * DK + 4);
    s.a0a = *(const float4*)(pa);
    s.a0b = *(const float4*)(pa + 4);
    s.a1a = *(const float4*)(pa + (size_t)64 * DK);
    s.a1b = *(const float4*)(pa + (size_t)64 * DK + 4);
    return s;
  };

  auto store_stage = [&](const Stage& s) {
    *(bf16x8*)(Xs + woff)            = pack8(s.x0a, s.x0b);
    *(bf16x8*)(Xs + woff + 64 * 32)  = pack8(s.x1a, s.x1b);
    *(bf16x8*)(As + woff)            = pack8(s.a0a, s.a0b);
    *(bf16x8*)(As + woff + 64 * 32)  = pack8(s.a1a, s.a1b);
  };

  auto compute = [&]() {
    bf16x8 af[4], bfr[4];
#pragma unroll
    for (int m = 0; m < 4; ++m)
      af[m] = *(const bf16x8*)(Xs + aoff + m * 16 * 32);
#pragma unroll
    for (int n = 0; n < 4; ++n)
      bfr[n] = *(const bf16x8*)(As + boff + n * 16 * 32);
#pragma unroll
    for (int m = 0; m < 4; ++m)
#pragma unroll
      for (int n = 0; n < 4; ++n)
        acc[m][n] = __builtin_amdgcn_mfma_f32_16x16x32_bf16(af[m], bfr[n],
                                                            acc[m][n], 0, 0, 0);
  };

  Stage sa = load_tile(0), sb;

  for (int kt = 0; kt < 128; kt += 2) {
    __syncthreads();
    store_stage(sa);
    sb = load_tile(kt + 1);
    __syncthreads();
    compute();
    __syncthreads();
    store_stage(sb);
    if (kt + 2 < 128) sa = load_tile(kt + 2);
    __syncthreads();
    compute();
  }

  float v[4][4];
#pragma unroll
  for (int m = 0; m < 4; ++m)
#pragma unroll
    for (int j = 0; j < 4; ++j) {
      float s = 0.f;
#pragma unroll
      for (int n = 0; n < 4; ++n) {
        float c = acc[m][n][j];
        s += c * c;
      }
      s += __shfl_xor(s, 1, 64);
      s += __shfl_xor(s, 2, 64);
      s += __shfl_xor(s, 4, 64);
      s += __shfl_xor(s, 8, 64);
      v[m][j] = s;
    }

  if (l15 == 0) {
#pragma unroll
    for (int m = 0; m < 4; ++m)
#pragma unroll
      for (int j = 0; j < 4; ++j)
        rowsum[wc][wr * 64 + m * 16 + lg * 4 + j] = v[m][j];
  }
  __syncthreads();

  if (t < 128) {
    float p = rowsum[0][t] + rowsum[1][t];
    atomicAdd(&out[tile_m * 128 + t], p);
  }
}

extern "C" void kernel_launch(void* const* d_in, const int* in_sizes, int n_in,
                              void* d_out, int out_size, void* d_ws, size_t ws_size,
                              hipStream_t stream) {
  const float* x = (const float*)d_in[0];
  const float* A = (const float*)d_in[1];
  float* out = (float*)d_out;

  hipMemsetAsync(out, 0, (size_t)out_size * sizeof(float), stream);

  if (ws_size >= WS_NEED) {
    __bf16* wsX = (__bf16*)d_ws;
    __bf16* wsW = wsX + X_ELEMS;
    hipLaunchKernelGGL(convX, dim3(2048), dim3(256), 0, stream, x, wsX);
    hipLaunchKernelGGL(convW, dim3(2048), dim3(256), 0, stream, A, wsW);
    hipLaunchKernelGGL(gemm8, dim3(512), dim3(512), 0, stream, wsX, wsW, out);
  } else {
    hipLaunchKernelGGL(gemm_rowsq, dim3(2048), dim3(256), 0, stream, x, A, out);
  }
}

// Round 5
// 269.753 us; speedup vs baseline: 2.2305x; 1.0065x over previous
//
#include <hip/hip_runtime.h>

typedef __bf16 bf16x8 __attribute__((ext_vector_type(8)));
typedef float  f32x4  __attribute__((ext_vector_type(4)));

#define NROWS 8192
#define DK    4096
#define MCOLS 4096
#define NKT   64            // K-tiles of BK=64
#define IMG   16384         // bf16 elems per 256x64 tile image (32 KB)
#define X_TILES 32
#define W_TILES 16

#define X_ELEMS ((size_t)NROWS * DK)
#define A_ELEMS ((size_t)MCOLS * DK)
#define WS_NEED ((X_ELEMS + A_ELEMS) * 2)

#define BAR()  do { __builtin_amdgcn_s_barrier(); asm volatile("" ::: "memory"); } while (0)
#define LGKM0  asm volatile("s_waitcnt lgkmcnt(0)" ::: "memory")
#define VM(n)  asm volatile("s_waitcnt vmcnt(" #n ")" ::: "memory")

__device__ __forceinline__ bf16x8 pack8(const float4& a, const float4& b) {
  bf16x8 r;
  r[0] = (__bf16)a.x; r[1] = (__bf16)a.y; r[2] = (__bf16)a.z; r[3] = (__bf16)a.w;
  r[4] = (__bf16)b.x; r[5] = (__bf16)b.y; r[6] = (__bf16)b.z; r[7] = (__bf16)b.w;
  return r;
}

__device__ __forceinline__ void gload16(const __bf16* g, __bf16* l) {
  __builtin_amdgcn_global_load_lds(
      (const __attribute__((address_space(1))) void*)g,
      (__attribute__((address_space(3))) void*)l, 16, 0, 0);
}

// ---- converts: fp32 row-major -> bf16 fragment-major tile images -----------
// X image slot = mh*8 + wr4*2 + m2  (m_frag = wr4*4 + mh*2 + m2)
__global__ __launch_bounds__(256) void convX(const float* __restrict__ src,
                                             __bf16* __restrict__ dst) {
  const int total = X_TILES * NKT * 2048;
  for (int i = blockIdx.x * blockDim.x + threadIdx.x; i < total;
       i += gridDim.x * blockDim.x) {
    int lane = i & 63;
    int kc   = (i >> 6) & 1;
    int slot = (i >> 7) & 15;
    int kt   = (i >> 11) & 63;
    int tm   = i >> 17;
    int mh = slot >> 3, wr4 = (slot >> 1) & 3, m2 = slot & 1;
    int mfrag = wr4 * 4 + mh * 2 + m2;
    int row = tm * 256 + mfrag * 16 + (lane & 15);
    int k   = kt * 64 + kc * 32 + (lane >> 4) * 8;
    const float4* p = (const float4*)(src + (size_t)row * DK + k);
    float4 a = p[0], b = p[1];
    *(bf16x8*)(dst + (size_t)i * 8) = pack8(a, b);
  }
}

// W image slot = nh*8 + wc2*4 + n4  (n_frag = wc2*8 + nh*4 + n4)
__global__ __launch_bounds__(256) void convW(const float* __restrict__ src,
                                             __bf16* __restrict__ dst) {
  const int total = W_TILES * NKT * 2048;
  for (int i = blockIdx.x * blockDim.x + threadIdx.x; i < total;
       i += gridDim.x * blockDim.x) {
    int lane = i & 63;
    int kc   = (i >> 6) & 1;
    int slot = (i >> 7) & 15;
    int kt   = (i >> 11) & 63;
    int tn   = i >> 17;
    int nh = slot >> 3, wc2 = (slot >> 2) & 1, n4 = slot & 3;
    int nfrag = wc2 * 8 + nh * 4 + n4;
    int row = tn * 256 + nfrag * 16 + (lane & 15);
    int k   = kt * 64 + kc * 32 + (lane >> 4) * 8;
    const float4* p = (const float4*)(src + (size_t)row * DK + k);
    float4 a = p[0], b = p[1];
    *(bf16x8*)(dst + (size_t)i * 8) = pack8(a, b);
  }
}

// ---- 8-phase 256^2 GEMM + fused row-sum-of-squares -------------------------
__device__ __forceinline__ void readA(bf16x8 (&a)[2][2], const __bf16* p, int MH) {
#pragma unroll
  for (int m2 = 0; m2 < 2; ++m2)
#pragma unroll
    for (int kc = 0; kc < 2; ++kc)
      a[m2][kc] = *(const bf16x8*)(p + MH * 8192 + m2 * 1024 + kc * 512);
}

__device__ __forceinline__ void readB(bf16x8 (&b)[4][2], const __bf16* p, int NH) {
#pragma unroll
  for (int n4 = 0; n4 < 4; ++n4)
#pragma unroll
    for (int kc = 0; kc < 2; ++kc)
      b[n4][kc] = *(const bf16x8*)(p + NH * 8192 + n4 * 1024 + kc * 512);
}

// kc OUTER: dependent MFMAs on the same acc are 8 apart (was adjacent).
// Per-acc kc order (0 then 1) preserved -> numerics identical.
__device__ __forceinline__ void quad(f32x4 (&acc)[4][8], const bf16x8 (&a)[2][2],
                                     const bf16x8 (&b)[4][2], int MH, int NH) {
  __builtin_amdgcn_s_setprio(1);
#pragma unroll
  for (int kc = 0; kc < 2; ++kc)
#pragma unroll
    for (int m2 = 0; m2 < 2; ++m2)
#pragma unroll
      for (int n4 = 0; n4 < 4; ++n4)
        acc[MH * 2 + m2][NH * 4 + n4] = __builtin_amdgcn_mfma_f32_16x16x32_bf16(
            a[m2][kc], b[n4][kc], acc[MH * 2 + m2][NH * 4 + n4], 0, 0, 0);
  __builtin_amdgcn_s_setprio(0);
}

__global__ __launch_bounds__(512, 2) void gemm8(const __bf16* __restrict__ wsX,
                                                const __bf16* __restrict__ wsW,
                                                float* __restrict__ out) {
  __shared__ __align__(16) __bf16 Xls[2][IMG];   // 64 KB
  __shared__ __align__(16) __bf16 Wls[2][IMG];   // 64 KB
  __shared__ float rowsum[2][256];

  const int t    = threadIdx.x;
  const int lane = t & 63;
  const int w    = t >> 6;           // 0..7
  const int wr4  = w >> 1;           // 0..3 : rows wr4*64..+63
  const int wc2  = w & 1;            // 0..1 : cols wc2*128..+127
  const int l15  = lane & 15;
  const int lg   = lane >> 4;

  // XCD-aware mapping with ~square concurrent windows: each XCD owns an
  // 8m x 8n tile region; the ~32 concurrently-running blocks (1/CU) cover
  // 8m x 4n (24 MB unique operand data; synchronized K-progress lets L2
  // absorb concurrent re-reads of each 64KB K-slice).
  unsigned bid = blockIdx.x;
  unsigned xcd = bid & 7, seq = bid >> 3;            // seq 0..63
  const int tile_m = (int)((xcd >> 1) * 8 + (seq & 7));    // 0..31
  const int tile_n = (int)((xcd & 1) * 8 + (seq >> 3));    // 0..15

  const __bf16* xbase = wsX + (size_t)tile_m * ((size_t)NKT * IMG);
  const __bf16* wbase = wsW + (size_t)tile_n * ((size_t)NKT * IMG);

  const __bf16* pX0 = &Xls[0][0] + wr4 * 2048 + lane * 8;
  const __bf16* pX1 = &Xls[1][0] + wr4 * 2048 + lane * 8;
  const __bf16* pW0 = &Wls[0][0] + wc2 * 4096 + lane * 8;
  const __bf16* pW1 = &Wls[1][0] + wc2 * 4096 + lane * 8;

  f32x4 acc[4][8] = {};
  bf16x8 a[2][2], b0[4][2], b1[4][2];

  auto stage = [&](const __bf16* srcImg, int regionOff, __bf16* ldsImg) {
    const __bf16* s0 = srcImg + regionOff + t * 8;
    __bf16* d0 = ldsImg + regionOff + w * 512;   // wave-uniform dst
    gload16(s0, d0);
    gload16(s0 + 4096, d0 + 4096);
  };

  // prologue: prime 6 region-stages in steady-state FIFO order
  stage(xbase,          0, &Xls[0][0]);   // X0(0)   s1
  stage(wbase,          0, &Wls[0][0]);   // W0(0)   s2
  stage(xbase,       8192, &Xls[0][0]);   // X1(0)   s3
  stage(wbase,       8192, &Wls[0][0]);   // W1(0)   s4
  stage(xbase + IMG,    0, &Xls[1][0]);   // X0(1)   s5
  stage(wbase + IMG,    0, &Wls[1][0]);   // W0(1)   s6
  VM(8);                                  // own X0(0),W0(0) landed
  BAR();                                  // ALL waves' X0(0),W0(0) landed

  for (int it = 0; it < 31; ++it) {
    const int h0 = 2 * it;
    const __bf16* xi1 = xbase + (size_t)(h0 + 1) * IMG;
    const __bf16* wi1 = wbase + (size_t)(h0 + 1) * IMG;
    const __bf16* xi2 = xbase + (size_t)(h0 + 2) * IMG;
    const __bf16* wi2 = wbase + (size_t)(h0 + 2) * IMG;
    const __bf16* xi3 = xbase + (size_t)(h0 + 3) * IMG;
    const __bf16* wi3 = wbase + (size_t)(h0 + 3) * IMG;

    // ---- half-iter A: tile h0 in buf0 ----
    // ph1 (X0,W0 of h0 guaranteed by previous VM(8)+BAR)
    readA(a, pX0, 0); readB(b0, pW0, 0);
    stage(xi1, 8192, &Xls[1][0]);                 // X1(h0+1) -> buf1
    BAR(); LGKM0; quad(acc, a, b0, 0, 0); VM(6); BAR();   // forces X1,W1(h0)
    // ph2
    readB(b1, pW0, 1);
    stage(wi1, 8192, &Wls[1][0]);                 // W1(h0+1) -> buf1
    BAR(); LGKM0; quad(acc, a, b1, 0, 1); BAR();
    // ph3
    readA(a, pX0, 1);
    stage(xi2, 0, &Xls[0][0]);                    // X0(h0+2) -> buf0
    BAR(); LGKM0; quad(acc, a, b0, 1, 0); BAR();
    // ph4
    stage(wi2, 0, &Wls[0][0]);                    // W0(h0+2) -> buf0
    BAR(); quad(acc, a, b1, 1, 1); VM(8); BAR();  // forces X0,W0(h0+1)

    // ---- half-iter B: tile h0+1 in buf1 ----
    // ph5
    readA(a, pX1, 0); readB(b0, pW1, 0);
    stage(xi2, 8192, &Xls[0][0]);                 // X1(h0+2) -> buf0
    BAR(); LGKM0; quad(acc, a, b0, 0, 0); VM(6); BAR();   // forces X1,W1(h0+1)
    // ph6
    readB(b1, pW1, 1);
    stage(wi2, 8192, &Wls[0][0]);                 // W1(h0+2) -> buf0
    BAR(); LGKM0; quad(acc, a, b1, 0, 1); BAR();
    // ph7
    readA(a, pX1, 1);
    stage(xi3, 0, &Xls[1][0]);                    // X0(h0+3) -> buf1
    BAR(); LGKM0; quad(acc, a, b0, 1, 0); BAR();
    // ph8
    stage(wi3, 0, &Wls[1][0]);                    // W0(h0+3) -> buf1
    BAR(); quad(acc, a, b1, 1, 1); VM(8); BAR();  // forces X0,W0(h0+2)
  }

  // ---- peeled tail: it = 31 (tiles 62 in buf0, 63 in buf1) ----
  {
    const __bf16* xi1 = xbase + (size_t)63 * IMG;
    const __bf16* wi1 = wbase + (size_t)63 * IMG;

    // ph1 (X0,W0(62) ready)
    readA(a, pX0, 0); readB(b0, pW0, 0);
    stage(xi1, 8192, &Xls[1][0]);                 // X1(63) -> buf1
    BAR(); LGKM0; quad(acc, a, b0, 0, 0); VM(6); BAR();   // forces X1,W1(62)
    // ph2
    readB(b1, pW0, 1);
    stage(wi1, 8192, &Wls[1][0]);                 // W1(63) -> buf1
    BAR(); LGKM0; quad(acc, a, b1, 0, 1); BAR();
    // ph3
    readA(a, pX0, 1);
    BAR(); LGKM0; quad(acc, a, b0, 1, 0); BAR();
    // ph4
    BAR(); quad(acc, a, b1, 1, 1); VM(4); BAR();  // forces X0,W0(63)
    // ph5
    readA(a, pX1, 0); readB(b0, pW1, 0);
    BAR(); LGKM0; quad(acc, a, b0, 0, 0); VM(0); BAR();   // forces X1,W1(63)
    // ph6
    readB(b1, pW1, 1);
    BAR(); LGKM0; quad(acc, a, b1, 0, 1); BAR();
    // ph7
    readA(a, pX1, 1);
    BAR(); LGKM0; quad(acc, a, b0, 1, 0); BAR();
    // ph8
    quad(acc, a, b1, 1, 1);
  }

  // ---- epilogue: row sums of squares ----
  // acc[mr][nc][j]: row = tile_m*256 + (wr4*4+mr)*16 + lg*4 + j
  float v[4][4];
#pragma unroll
  for (int mr = 0; mr < 4; ++mr)
#pragma unroll
    for (int j = 0; j < 4; ++j) {
      float s = 0.f;
#pragma unroll
      for (int nc = 0; nc < 8; ++nc) {
        float c = acc[mr][nc][j];
        s += c * c;
      }
      s += __shfl_xor(s, 1, 64);
      s += __shfl_xor(s, 2, 64);
      s += __shfl_xor(s, 4, 64);
      s += __shfl_xor(s, 8, 64);
      v[mr][j] = s;
    }

  if (l15 == 0) {
#pragma unroll
    for (int mr = 0; mr < 4; ++mr)
#pragma unroll
      for (int j = 0; j < 4; ++j)
        rowsum[wc2][(wr4 * 4 + mr) * 16 + lg * 4 + j] = v[mr][j];
  }
  __syncthreads();

  if (t < 256) {
    float p = rowsum[0][t] + rowsum[1][t];
    atomicAdd(&out[tile_m * 256 + t], p);
  }
}

// ---------------- fallback (direct fp32 path, used only if ws too small) ----
struct Stage {
  float4 x0a, x0b, x1a, x1b;
  float4 a0a, a0b, a1a, a1b;
};

__global__ __launch_bounds__(256) void gemm_rowsq(const float* __restrict__ X,
                                                  const float* __restrict__ A,
                                                  float* __restrict__ out) {
  __shared__ __align__(16) __bf16 Xs[128 * 32];
  __shared__ __align__(16) __bf16 As[128 * 32];
  __shared__ float rowsum[2][128];

  const int t    = threadIdx.x;
  const int lane = t & 63;
  const int wid  = t >> 6;
  const int wr   = wid >> 1;
  const int wc   = wid & 1;
  const int l15  = lane & 15;
  const int lg   = lane >> 4;

  unsigned bid = blockIdx.x;
  unsigned swz = (bid & 7) * 256u + (bid >> 3);
  const int tile_m = swz >> 5;
  const int tile_n = swz & 31;

  const int srow = t >> 2;
  const int sc   = t & 3;
  const int cw   = sc ^ ((t >> 3) & 3);
  const int woff = srow * 32 + cw * 8;

  const float* gx = X + (size_t)(tile_m * 128 + srow) * DK + sc * 8;
  const float* ga = A + (size_t)(tile_n * 128 + srow) * DK + sc * 8;

  const int chA  = lg ^ ((l15 >> 1) & 3);
  const int aoff = (wr * 64 + l15) * 32 + chA * 8;
  const int boff = (wc * 64 + l15) * 32 + chA * 8;

  f32x4 acc[4][4] = {};

  auto load_tile = [&](int kt) {
    Stage s;
    const float* px = gx + kt * 32;
    const float* pa = ga + kt * 32;
    s.x0a = *(const float4*)(px);
    s.x0b = *(const float4*)(px + 4);
    s.x1a = *(const float4*)(px + (size_t)64 * DK);
    s.x1b = *(const float4*)(px + (size_t)64 * DK + 4);
    s.a0a = *(const float4*)(pa);
    s.a0b = *(const float4*)(pa + 4);
    s.a1a = *(const float4*)(pa + (size_t)64 * DK);
    s.a1b = *(const float4*)(pa + (size_t)64 * DK + 4);
    return s;
  };

  auto store_stage = [&](const Stage& s) {
    *(bf16x8*)(Xs + woff)            = pack8(s.x0a, s.x0b);
    *(bf16x8*)(Xs + woff + 64 * 32)  = pack8(s.x1a, s.x1b);
    *(bf16x8*)(As + woff)            = pack8(s.a0a, s.a0b);
    *(bf16x8*)(As + woff + 64 * 32)  = pack8(s.a1a, s.a1b);
  };

  auto compute = [&]() {
    bf16x8 af[4], bfr[4];
#pragma unroll
    for (int m = 0; m < 4; ++m)
      af[m] = *(const bf16x8*)(Xs + aoff + m * 16 * 32);
#pragma unroll
    for (int n = 0; n < 4; ++n)
      bfr[n] = *(const bf16x8*)(As + boff + n * 16 * 32);
#pragma unroll
    for (int m = 0; m < 4; ++m)
#pragma unroll
      for (int n = 0; n < 4; ++n)
        acc[m][n] = __builtin_amdgcn_mfma_f32_16x16x32_bf16(af[m], bfr[n],
                                                            acc[m][n], 0, 0, 0);
  };

  Stage sa = load_tile(0), sb;

  for (int kt = 0; kt < 128; kt += 2) {
    __syncthreads();
    store_stage(sa);
    sb = load_tile(kt + 1);
    __syncthreads();
    compute();
    __syncthreads();
    store_stage(sb);
    if (kt + 2 < 128) sa = load_tile(kt + 2);
    __syncthreads();
    compute();
  }

  float v[4][4];
#pragma unroll
  for (int m = 0; m < 4; ++m)
#pragma unroll
    for (int j = 0; j < 4; ++j) {
      float s = 0.f;
#pragma unroll
      for (int n = 0; n < 4; ++n) {
        float c = acc[m][n][j];
        s += c * c;
      }
      s += __shfl_xor(s, 1, 64);
      s += __shfl_xor(s, 2, 64);
      s += __shfl_xor(s, 4, 64);
      s += __shfl_xor(s, 8, 64);
      v[m][j] = s;
    }

  if (l15 == 0) {
#pragma unroll
    for (int m = 0; m < 4; ++m)
#pragma unroll
      for (int j = 0; j < 4; ++j)
        rowsum[wc][wr * 64 + m * 16 + lg * 4 + j] = v[m][j];
  }
  __syncthreads();

  if (t < 128) {
    float p = rowsum[0][t] + rowsum[1][t];
    atomicAdd(&out[tile_m * 128 + t], p);
  }
}

extern "C" void kernel_launch(void* const* d_in, const int* in_sizes, int n_in,
                              void* d_out, int out_size, void* d_ws, size_t ws_size,
                              hipStream_t stream) {
  const float* x = (const float*)d_in[0];
  const float* A = (const float*)d_in[1];
  float* out = (float*)d_out;

  hipMemsetAsync(out, 0, (size_t)out_size * sizeof(float), stream);

  if (ws_size >= WS_NEED) {
    __bf16* wsX = (__bf16*)d_ws;
    __bf16* wsW = wsX + X_ELEMS;
    hipLaunchKernelGGL(convX, dim3(2048), dim3(256), 0, stream, x, wsX);
    hipLaunchKernelGGL(convW, dim3(2048), dim3(256), 0, stream, A, wsW);
    hipLaunchKernelGGL(gemm8, dim3(512), dim3(512), 0, stream, wsX, wsW, out);
  } else {
    hipLaunchKernelGGL(gemm_rowsq, dim3(2048), dim3(256), 0, stream, x, A, out);
  }
}